// Round 3
// baseline (276.674 us; speedup 1.0000x reference)
//
#include <hip/hip_runtime.h>
#include <hip/hip_bf16.h>

// Squared Euclidean distance: out[i][j] = ||a_i||^2 + ||b_j||^2 - 2 a_i.b_j
// a: [8192,128] fp32, b: [8192,128] fp32, out: [8192,8192] fp32.
//
// v4: workspace is too small for pre-converted bf16 copies (v3's fast path
// never ran), so convert in-kernel but fix the two measured/derived costs of
// the round-0 kernel:
//   1. LDS XOR-swizzle (byte ^= (row&7)<<4) on BOTH write and read sides:
//      unswizzled ds_read_b128 at 256B row stride served 1 KiB from only 16
//      banks (16 phases); swizzled = optimal 8 phases.  (reg-staged writes, so
//      no global_load_lds linearity constraint — rule #21 satisfied)
//   2. Packed bf16 convert via __float22bfloat162_rn (v_cvt_pk_bf16_f32),
//      ~4x less staging VALU than the bit-twiddle f2bf.
//   3. Single K=128 stage (64 KiB LDS, 2 blocks/CU) — one barrier pair,
//      cross-block overlap hides staging + epilogue.
// Write-bound floor: 256 MiB out @6.3TB/s => ~43us for dist_kernel.

typedef __attribute__((ext_vector_type(8))) short bf16x8;   // 8 bf16 = 4 VGPRs
typedef __attribute__((ext_vector_type(4))) float f32x4;    // MFMA acc

// ---------------- kernel 1: exact fp32 row norms ----------------
// one wave (64 lanes) per row of 128 floats: lane reads float2, shuffle-reduce.
__global__ void norms_kernel(const float* __restrict__ m1,
                             const float* __restrict__ m2,
                             float* __restrict__ n1,
                             float* __restrict__ n2,
                             int rows1, int rows2) {
    int gwave = (int)((blockIdx.x * blockDim.x + threadIdx.x) >> 6);
    int lane  = threadIdx.x & 63;
    const float* src;
    float* dst;
    int row;
    if (gwave < rows1) { src = m1; dst = n1; row = gwave; }
    else {
        row = gwave - rows1;
        if (row >= rows2) return;
        src = m2; dst = n2;
    }
    const float2* p = (const float2*)(src + (size_t)row * 128);
    float2 v = p[lane];
    float s = v.x * v.x + v.y * v.y;
#pragma unroll
    for (int off = 32; off; off >>= 1) s += __shfl_xor(s, off, 64);
    if (lane == 0) dst[row] = s;
}

// ---------------- kernel 2: bf16 MFMA cross-term + epilogue ----------------
#define BM 128
#define BN 128
// full K = 128 staged at once: As 128x128 bf16 = 32 KiB, Bs 32 KiB.

__device__ __forceinline__ bf16x8 cvt8(float4 v0, float4 v1) {
    union { bf16x8 v; __hip_bfloat162 h[4]; } u;
    u.h[0] = __float22bfloat162_rn(make_float2(v0.x, v0.y));
    u.h[1] = __float22bfloat162_rn(make_float2(v0.z, v0.w));
    u.h[2] = __float22bfloat162_rn(make_float2(v1.x, v1.y));
    u.h[3] = __float22bfloat162_rn(make_float2(v1.z, v1.w));
    return u.v;
}

__global__ __launch_bounds__(256, 2)
void dist_kernel(const float* __restrict__ A, const float* __restrict__ B,
                 const float* __restrict__ n1, const float* __restrict__ n2,
                 float* __restrict__ out, int N2) {
    __shared__ char lds[65536];            // [0,32K) = A tile, [32K,64K) = B tile

    const int tid  = threadIdx.x;
    const int wave = tid >> 6;             // 0..3
    const int lane = tid & 63;
    const int q    = lane >> 4;            // quad 0..3
    const int l15  = lane & 15;

    const int ti = blockIdx.y * BM;        // rows of mat1
    const int tj = blockIdx.x * BN;        // rows of mat2 (= cols of out)

    // ---- stage A and B tiles: fp32 -> bf16 (packed cvt), swizzled LDS write
    // Each thread handles 8 chunks of 8 elements per matrix.
    // LDS element (row, k) lives at byte  row*256 + ((2k) ^ ((row&7)<<4)).
#pragma unroll
    for (int g = 0; g < 8; ++g) {
        int idx = tid + g * 256;           // 0..2047
        int row = idx >> 4;                // 0..127
        int ke  = (idx & 15) * 8;          // element col of 8-elem chunk
        int sw  = (ke * 2) ^ ((row & 7) << 4);
        const float4* pa = (const float4*)(A + (size_t)(ti + row) * 128 + ke);
        *(bf16x8*)(lds + row * 256 + sw) = cvt8(pa[0], pa[1]);
    }
#pragma unroll
    for (int g = 0; g < 8; ++g) {
        int idx = tid + g * 256;
        int row = idx >> 4;
        int ke  = (idx & 15) * 8;
        int sw  = (ke * 2) ^ ((row & 7) << 4);
        const float4* pb = (const float4*)(B + (size_t)(tj + row) * 128 + ke);
        *(bf16x8*)(lds + 32768 + row * 256 + sw) = cvt8(pb[0], pb[1]);
    }
    __syncthreads();

    const int wm = (wave >> 1) * 64;       // wave's 64x64 sub-tile
    const int wn = (wave & 1) * 64;

    f32x4 acc[4][4] = {};                  // zero-init

    // ---- MFMA over K=128 ----
    // A frag: lane holds A[m = l15][k = q*8+j]; B frag: B[k = q*8+j][n = l15]
    // bf16x8 = 16B/lane; swizzled cols give the optimal 8-phase b128 read.
    const char* Abase = lds;
    const char* Bbase = lds + 32768;
#pragma unroll
    for (int kk = 0; kk < 128; kk += 32) {
        const int cb = kk * 2 + q * 16;    // byte col of this lane's 8 bf16
        bf16x8 af[4], bfr[4];
#pragma unroll
        for (int mi = 0; mi < 4; ++mi) {
            int row = wm + mi * 16 + l15;
            af[mi] = *(const bf16x8*)(Abase + row * 256 + (cb ^ ((row & 7) << 4)));
        }
#pragma unroll
        for (int ni = 0; ni < 4; ++ni) {
            int row = wn + ni * 16 + l15;
            bfr[ni] = *(const bf16x8*)(Bbase + row * 256 + (cb ^ ((row & 7) << 4)));
        }
#pragma unroll
        for (int mi = 0; mi < 4; ++mi)
#pragma unroll
            for (int ni = 0; ni < 4; ++ni)
                acc[mi][ni] = __builtin_amdgcn_mfma_f32_16x16x32_bf16(
                    af[mi], bfr[ni], acc[mi][ni], 0, 0, 0);
    }

    // ---- epilogue: out = n1[r] + n2[c] - 2*cross ----
    // C/D layout: col = l15, row = q*4 + reg  (verified m89/m91)
#pragma unroll
    for (int mi = 0; mi < 4; ++mi) {
        int r0 = ti + wm + mi * 16 + q * 4;
        float a0 = n1[r0 + 0], a1 = n1[r0 + 1], a2 = n1[r0 + 2], a3 = n1[r0 + 3];
#pragma unroll
        for (int ni = 0; ni < 4; ++ni) {
            int c = tj + wn + ni * 16 + l15;
            float nb = n2[c];
            f32x4 v = acc[mi][ni];
            out[(size_t)(r0 + 0) * N2 + c] = a0 + nb - 2.0f * v[0];
            out[(size_t)(r0 + 1) * N2 + c] = a1 + nb - 2.0f * v[1];
            out[(size_t)(r0 + 2) * N2 + c] = a2 + nb - 2.0f * v[2];
            out[(size_t)(r0 + 3) * N2 + c] = a3 + nb - 2.0f * v[3];
        }
    }
}

extern "C" void kernel_launch(void* const* d_in, const int* in_sizes, int n_in,
                              void* d_out, int out_size, void* d_ws, size_t ws_size,
                              hipStream_t stream) {
    const float* m1 = (const float*)d_in[0];
    const float* m2 = (const float*)d_in[1];
    float* out = (float*)d_out;
    const int rows1 = in_sizes[0] / 128;   // 8192
    const int rows2 = in_sizes[1] / 128;   // 8192

    float* n1 = (float*)d_ws;              // norms only: 64 KiB of workspace
    float* n2 = n1 + rows1;

    int total_waves = rows1 + rows2;
    int nb = (total_waves * 64 + 255) / 256;
    norms_kernel<<<nb, 256, 0, stream>>>(m1, m2, n1, n2, rows1, rows2);

    dim3 grid(rows2 / BN, rows1 / BM);
    dist_kernel<<<grid, 256, 0, stream>>>(m1, m2, n1, n2, out, rows2);
}